// Round 1
// baseline (468.021 us; speedup 1.0000x reference)
//
#include <hip/hip_runtime.h>

// CubePad: x [N*6, C, H, W] f32 -> out [N*6, C, H+2, W+2] f32, pad=1.
// Face order: 0=front, 1=right, 2=back, 3=left, 4=top, 5=down.

#define C_  64
#define H_  256
#define W_  256
#define HP  (H_ + 2)
#define WP  (W_ + 2)
#define FACE_STRIDE (C_ * H_ * W_)

__global__ void cubepad_kernel(const float* __restrict__ x,
                               float* __restrict__ out, int total) {
  const int stride = gridDim.x * blockDim.x;
  for (int idx = blockIdx.x * blockDim.x + threadIdx.x; idx < total; idx += stride) {
    int w  = idx % WP;
    int t1 = idx / WP;
    int h  = t1 % HP;
    int t2 = t1 / HP;
    int c  = t2 % C_;
    int fg = t2 / C_;
    int face = fg % 6;
    int nb   = fg / 6;

    // base points at (cube nb, channel c) of face 0; IN adds face offset.
    const float* base = x + (size_t)nb * 6 * FACE_STRIDE + (size_t)c * (H_ * W_);
#define IN(f, hh, ww) base[(size_t)(f) * FACE_STRIDE + (hh) * W_ + (ww)]

    float v;
    if (h > 0 && h < HP - 1 && w > 0 && w < WP - 1) {
      // interior: plain copy
      v = IN(face, h - 1, w - 1);
    } else if (h == 0) {
      // top plate (corners = clamped wi, since p_t == p_l == p_r == 1)
      int wi = w - 1;
      wi = wi < 0 ? 0 : (wi > W_ - 1 ? W_ - 1 : wi);
      switch (face) {
        case 0:  v = IN(4, H_ - 1, wi);           break;  // top's last row
        case 1:  v = IN(4, H_ - 1 - wi, W_ - 1);  break;
        case 2:  v = IN(4, 0, W_ - 1 - wi);       break;
        case 3:  v = IN(4, wi, 0);                break;
        case 4:  v = IN(2, 0, W_ - 1 - wi);       break;  // back's first row, flipped
        default: v = IN(0, H_ - 1, wi);           break;  // front's last row
      }
    } else if (h == HP - 1) {
      // down plate
      int wi = w - 1;
      wi = wi < 0 ? 0 : (wi > W_ - 1 ? W_ - 1 : wi);
      switch (face) {
        case 0:  v = IN(5, 0, wi);                 break;
        case 1:  v = IN(5, wi, W_ - 1);            break;
        case 2:  v = IN(5, H_ - 1, W_ - 1 - wi);   break;
        case 3:  v = IN(5, H_ - 1 - wi, 0);        break;
        case 4:  v = IN(0, 0, wi);                 break;  // front's first row
        default: v = IN(2, H_ - 1, W_ - 1 - wi);   break;  // back's last row, flipped
      }
    } else if (w == 0) {
      // left plate, h in [1, H]
      int hi = h - 1;
      switch (face) {
        case 0:  v = IN(3, hi, W_ - 1);            break;  // left's last col
        case 1:  v = IN(0, hi, W_ - 1);            break;
        case 2:  v = IN(1, hi, W_ - 1);            break;
        case 3:  v = IN(2, hi, W_ - 1);            break;
        case 4:  v = IN(3, 0, hi);                 break;  // left's first row, transposed
        default: v = IN(3, H_ - 1, W_ - 1 - hi);   break;  // left's last row, reversed
      }
    } else {
      // right plate (w == WP-1), h in [1, H]
      int hi = h - 1;
      switch (face) {
        case 0:  v = IN(1, hi, 0);                 break;  // right's first col
        case 1:  v = IN(2, hi, 0);                 break;
        case 2:  v = IN(3, hi, 0);                 break;
        case 3:  v = IN(0, hi, 0);                 break;
        case 4:  v = IN(1, 0, W_ - 1 - hi);        break;  // right's first row, reversed
        default: v = IN(1, H_ - 1, hi);            break;  // right's last row, transposed
      }
    }
#undef IN
    out[idx] = v;
  }
}

extern "C" void kernel_launch(void* const* d_in, const int* in_sizes, int n_in,
                              void* d_out, int out_size, void* d_ws, size_t ws_size,
                              hipStream_t stream) {
  const float* x = (const float*)d_in[0];
  float* out = (float*)d_out;
  const int total = out_size;  // 12 * 64 * 258 * 258
  const int threads = 256;
  const int blocks = 2048;
  cubepad_kernel<<<blocks, threads, 0, stream>>>(x, out, total);
}

// Round 4
// 418.554 us; speedup vs baseline: 1.1182x; 1.1182x over previous
//
#include <hip/hip_runtime.h>

// CubePad: x [N*6, C, 256, 256] f32 -> out [N*6, C, 258, 258] f32, pad=1.
// Face order: 0=front, 1=right, 2=back, 3=left, 4=top, 5=down.
// Single kernel; one output row per 256-thread block; wave-uniform index math.

#define C_  64
#define H_  256
#define W_  256
#define HP  258
#define WP  258
#define FACE_STRIDE (C_ * H_ * W_)   // 4,194,304
#define PLANE_IN  (H_ * W_)          // 65,536
#define PLANE_OUT (HP * WP)          // 66,564

__global__ void cubepad_row_kernel(const float* __restrict__ x,
                                   float* __restrict__ out) {
  const int t   = threadIdx.x;   // 0..255
  const int h   = blockIdx.x;    // 0..257 (output row)
  const int fgc = blockIdx.y;    // 0..767 = (nb*6+face)*64 + c
  const int fg  = fgc >> 6;
  const int c   = fgc & 63;
  const int face = fg < 6 ? fg : fg - 6;
  const int nb   = fg < 6 ? 0 : 1;

  const float* base = x + (size_t)nb * 6 * FACE_STRIDE + (size_t)c * PLANE_IN;
  float* orow = out + (size_t)fgc * PLANE_OUT + (size_t)h * WP;
#define IN(f, hh, ww) base[(size_t)(f) * FACE_STRIDE + (hh) * W_ + (ww)]

  if (h > 0 && h < HP - 1) {
    const int hi = h - 1;
    // interior: w = t+1, coalesced row copy
    orow[t + 1] = IN(face, hi, t);
    if (t == 0) {            // left halo, w = 0
      float v;
      switch (face) {
        case 0:  v = IN(3, hi, 255);       break;
        case 1:  v = IN(0, hi, 255);       break;
        case 2:  v = IN(1, hi, 255);       break;
        case 3:  v = IN(2, hi, 255);       break;
        case 4:  v = IN(3, 0, hi);         break;
        default: v = IN(3, 255, 255 - hi); break;
      }
      orow[0] = v;
    } else if (t == 255) {   // right halo, w = 257
      float v;
      switch (face) {
        case 0:  v = IN(1, hi, 0);         break;
        case 1:  v = IN(2, hi, 0);         break;
        case 2:  v = IN(3, hi, 0);         break;
        case 3:  v = IN(0, hi, 0);         break;
        case 4:  v = IN(1, 0, 255 - hi);   break;
        default: v = IN(1, 255, hi);       break;
      }
      orow[257] = v;
    }
  } else if (h == 0) {
    // top plate; corner w=0 duplicates w=1 (wi clamped), w=257 duplicates w=256
    const int wi = t;
    float v;
    switch (face) {
      case 0:  v = IN(4, 255, wi);        break;
      case 1:  v = IN(4, 255 - wi, 255);  break;
      case 2:  v = IN(4, 0, 255 - wi);    break;
      case 3:  v = IN(4, wi, 0);          break;
      case 4:  v = IN(2, 0, 255 - wi);    break;
      default: v = IN(0, 255, wi);        break;
    }
    orow[t + 1] = v;
    if (t == 0)   orow[0]   = v;
    if (t == 255) orow[257] = v;
  } else {
    // bottom plate (h == 257)
    const int wi = t;
    float v;
    switch (face) {
      case 0:  v = IN(5, 0, wi);          break;
      case 1:  v = IN(5, wi, 255);        break;
      case 2:  v = IN(5, 255, 255 - wi);  break;
      case 3:  v = IN(5, 255 - wi, 0);    break;
      case 4:  v = IN(0, 0, wi);          break;
      default: v = IN(2, 255, 255 - wi);  break;
    }
    orow[t + 1] = v;
    if (t == 0)   orow[0]   = v;
    if (t == 255) orow[257] = v;
  }
#undef IN
}

extern "C" void kernel_launch(void* const* d_in, const int* in_sizes, int n_in,
                              void* d_out, int out_size, void* d_ws, size_t ws_size,
                              hipStream_t stream) {
  const float* x = (const float*)d_in[0];
  float* out = (float*)d_out;
  dim3 grid(HP, 768);   // 258 rows x (12 face-groups * 64 channels)
  cubepad_row_kernel<<<grid, 256, 0, stream>>>(x, out);
}

// Round 5
// 339.373 us; speedup vs baseline: 1.3791x; 1.2333x over previous
//
#include <hip/hip_runtime.h>

// CubePad: x [N*6, C, 256, 256] f32 -> out [N*6, C, 258, 258] f32, pad=1.
// Face order: 0=front, 1=right, 2=back, 3=left, 4=top, 5=down.
// One aligned float4 output store per thread; unaligned float4 input load on
// the interior fast path; scalar gather fallback on plane borders.

#define C_  64
#define H_  256
#define W_  256
#define HP  258
#define WP  258
#define FACE_STRIDE (C_ * H_ * W_)   // 4,194,304
#define PLANE_IN  (H_ * W_)          // 65,536
#define PLANE_OUT (HP * WP)          // 66,564  (divisible by 4)
#define P4_PER_PLANE (PLANE_OUT / 4) // 16,641

typedef float f4  __attribute__((ext_vector_type(4)));              // 16B aligned
typedef float f4u __attribute__((ext_vector_type(4), aligned(4)));  // 4B aligned

__device__ __forceinline__ float value_at(const float* __restrict__ base,
                                          int face, int h, int w) {
#define IN(f, hh, ww) base[(size_t)(f) * FACE_STRIDE + (hh) * W_ + (ww)]
  if (h >= 1 && h <= H_ && w >= 1 && w <= W_) return IN(face, h - 1, w - 1);
  if (h == 0) {                       // top plate (corners via clamp)
    int wi = w - 1; wi = wi < 0 ? 0 : (wi > 255 ? 255 : wi);
    switch (face) {
      case 0:  return IN(4, 255, wi);
      case 1:  return IN(4, 255 - wi, 255);
      case 2:  return IN(4, 0, 255 - wi);
      case 3:  return IN(4, wi, 0);
      case 4:  return IN(2, 0, 255 - wi);
      default: return IN(0, 255, wi);
    }
  }
  if (h == HP - 1) {                  // bottom plate (corners via clamp)
    int wi = w - 1; wi = wi < 0 ? 0 : (wi > 255 ? 255 : wi);
    switch (face) {
      case 0:  return IN(5, 0, wi);
      case 1:  return IN(5, wi, 255);
      case 2:  return IN(5, 255, 255 - wi);
      case 3:  return IN(5, 255 - wi, 0);
      case 4:  return IN(0, 0, wi);
      default: return IN(2, 255, 255 - wi);
    }
  }
  int hi = h - 1;                     // h in [1,256]
  if (w == 0) {                       // left column
    switch (face) {
      case 0:  return IN(3, hi, 255);
      case 1:  return IN(0, hi, 255);
      case 2:  return IN(1, hi, 255);
      case 3:  return IN(2, hi, 255);
      case 4:  return IN(3, 0, hi);
      default: return IN(3, 255, 255 - hi);
    }
  }
  // right column (w == 257)
  switch (face) {
    case 0:  return IN(1, hi, 0);
    case 1:  return IN(2, hi, 0);
    case 2:  return IN(3, hi, 0);
    case 3:  return IN(0, hi, 0);
    case 4:  return IN(1, 0, 255 - hi);
    default: return IN(1, 255, hi);
  }
#undef IN
}

__global__ void cubepad_v4_kernel(const float* __restrict__ x,
                                  float* __restrict__ out) {
  int p4 = blockIdx.x * blockDim.x + threadIdx.x;
  if (p4 >= P4_PER_PLANE) return;
  const int fgc = blockIdx.y;          // 0..767
  const int fg  = fgc >> 6;
  const int c   = fgc & 63;
  const int face = fg < 6 ? fg : fg - 6;
  const int nb   = fg < 6 ? 0 : 1;
  const float* base = x + (size_t)nb * 6 * FACE_STRIDE + (size_t)c * PLANE_IN;

  const unsigned p = (unsigned)p4 << 2;     // flat offset in out plane
  const unsigned h = p / WP;                // compiler magic-div by 258
  const unsigned w = p - h * WP;

  f4 v;
  if (h >= 1u && h <= 256u && w >= 1u && w <= 253u) {
    // fast path: 4 interior elems, same row; contiguous (unaligned) 16B load
    v = *(const f4u*)(base + (size_t)face * FACE_STRIDE +
                      (size_t)(h - 1) * W_ + (w - 1));
  } else {
#pragma unroll
    for (int e = 0; e < 4; ++e) {
      unsigned pe = p + e;
      unsigned he = pe / WP;
      unsigned we = pe - he * WP;
      v[e] = value_at(base, face, (int)he, (int)we);
    }
  }
  *(f4*)(out + (size_t)fgc * PLANE_OUT + p) = v;   // aligned 16B store
}

extern "C" void kernel_launch(void* const* d_in, const int* in_sizes, int n_in,
                              void* d_out, int out_size, void* d_ws, size_t ws_size,
                              hipStream_t stream) {
  const float* x = (const float*)d_in[0];
  float* out = (float*)d_out;
  dim3 grid((P4_PER_PLANE + 255) / 256, 768);   // 66 x 768 blocks
  cubepad_v4_kernel<<<grid, 256, 0, stream>>>(x, out);
}